// Round 11
// baseline (65.152 us; speedup 1.0000x reference)
//
#include <hip/hip_runtime.h>

// x[2][4][128][128][128] f32, y[2][1][128][128][128] int32
constexpr int SPB = 1 << 21;
constexpr float EPSV = 1e-6f;

// Static scratch: packed per-voxel mask, 4 MB.
// mask[v] = (center_class << 4) | OR_{3x3x3 clipped}(1 << y[v+d])
__device__ unsigned char g_mask[2 * SPB];

// ===========================================================================
// K0: build packed 27-neighborhood presence mask + center class (proven R5)
// ===========================================================================
constexpr int K0_ZSEG = 4;
constexpr int K0_NBLK = (2 * (128 / K0_ZSEG) * 128) / 4;  // 2048

struct MEnt { int pk, cx, cy; };

__device__ __forceinline__ MEnt k0_load(const int* __restrict__ yb, int s,
                                        int rbase0, bool ym1, bool yp1) {
    MEnt e;
    const int rb = (s << 14) | rbase0;
    int2 vc = *(const int2*)(yb + rb);
    int nib0 = 1 << vc.x, nib1 = 1 << vc.y;
    if (ym1) { int2 vm = *(const int2*)(yb + rb - 128); nib0 |= 1 << vm.x; nib1 |= 1 << vm.y; }
    if (yp1) { int2 vp = *(const int2*)(yb + rb + 128); nib0 |= 1 << vp.x; nib1 |= 1 << vp.y; }
    e.pk = nib0 | (nib1 << 8);
    e.cx = vc.x; e.cy = vc.y;
    return e;
}

__global__ __launch_bounds__(256) void mask_build(const int* __restrict__ y32) {
    const int wid = (blockIdx.x << 2) | (threadIdx.x >> 6);
    const int lane = threadIdx.x & 63;
    const int yy = wid & 127;
    const int zs = (wid >> 7) & 31;
    const int b = (wid >> 12) & 1;
    const int x0 = lane << 1;
    const int z0 = zs * K0_ZSEG;
    const bool ym1 = yy > 0, yp1 = yy < 127;
    const int rbase0 = (yy << 7) | x0;

    const int* __restrict__ yb = y32 + ((long)b << 21);
    unsigned char* __restrict__ mb = g_mask + ((long)b << 21);

    MEnt e0, e1;
    if (z0 > 0) e0 = k0_load(yb, z0 - 1, rbase0, ym1, yp1);
    else { e0.pk = 0; e0.cx = 0; e0.cy = 0; }
    e1 = k0_load(yb, z0, rbase0, ym1, yp1);

#pragma unroll
    for (int dz = 0; dz < K0_ZSEG; ++dz) {
        const int z = z0 + dz;
        MEnt e2;
        if (z + 1 < 128) e2 = k0_load(yb, z + 1, rbase0, ym1, yp1);
        else { e2.pk = 0; e2.cx = 0; e2.cy = 0; }

        const int zor = e0.pk | e1.pk | e2.pk;
        int orL = __shfl_up(zor, 1);
        if (lane == 0) orL = 0;
        int orR = __shfl_down(zor, 1);
        if (lane == 63) orR = 0;
        const int full0 = (zor | (zor >> 8) | (orL >> 8)) & 15;
        const int full1 = (zor | (zor >> 8) | orR) & 15;

        const unsigned short st =
            (unsigned short)((full0 | (e1.cx << 4)) | ((full1 | (e1.cy << 4)) << 8));
        *(unsigned short*)(mb + ((z << 14) | rbase0)) = st;

        e0 = e1; e1 = e2;
    }
}

// ===========================================================================
// K1: LDS-staged block stencil, ring-of-4 slots, distance-2 global prefetch,
// and a COUNTED barrier: raw s_barrier + lgkmcnt(0) only, so the just-issued
// global loads stay in flight across the barrier (T4). __syncthreads would
// emit vmcnt(0) and drain them (the R10 mistake).
// Block = (plane, 8 rows, all x, 16 z-slices). 1024 blocks = 4/CU, one round.
// ===========================================================================
constexpr int ZC = 16;                         // output slices per block
constexpr int NBLK = 8 * 16 * (128 / ZC);      // 1024

__global__ __launch_bounds__(256) void lah_main(const float* __restrict__ x,
                                                float* __restrict__ acc) {
    __shared__ float raw[4][10][128];   // 20.5 KB: slot (slice & 3), rows r0-1..r0+8
    __shared__ float sred[4];

    const int bid = blockIdx.x;
    const int plane = bid & 7;            // -> XCD (round-robin dispatch)
    const int b = plane >> 2, cls = plane & 3;
    const int inner = bid >> 3;           // 0..127
    const int yc = inner & 15;
    const int zq = inner >> 4;            // 0..7
    const int r0 = yc * 8;
    const int z0 = zq * ZC;               // multiple of 16 -> z0 & 3 == 0
    const int t = threadIdx.x;
    const int rr = t >> 5;                // 0..7 (center-row index)
    const int xc = (t & 31) << 2;         // 0,4,...,124
    const int lane = t & 63;
    const int xrow = 8 + (t >> 5);        // only used when t < 64 -> rows 8,9

    const float* __restrict__ xp = x + ((long)plane << 21);
    const unsigned char* __restrict__ mb = g_mask + ((long)b << 21);
    const int mrow = (r0 + rr) << 7;

    const float4 Z4 = make_float4(0.f, 0.f, 0.f, 0.f);

    // load float4 of global slice k, local row i (0..9); OOB -> zeros (neutral)
    auto gload = [&](int k, int i) -> float4 {
        const int gr = r0 - 1 + i;
        if ((unsigned)k > 127u || (unsigned)gr > 127u)
            return make_float4(0.f, 0.f, 0.f, 0.f);
        return *(const float4*)(xp + ((k << 14) | (gr << 7) | xc));
    };
    auto stage_direct = [&](int k) {
        const int s = k & 3;
        *(float4*)&raw[s][rr][xc] = gload(k, rr);
        if (t < 64) *(float4*)&raw[s][xrow][xc] = gload(k, xrow);
    };
    // y-product of (1-x) over rows rr-1..rr+1 of slot s; center raw row -> cx
    auto yprod = [&](int s, float4& cx) -> float4 {
        const float4 a = *(const float4*)&raw[s][rr][xc];
        const float4 bq = *(const float4*)&raw[s][rr + 1][xc];
        const float4 c = *(const float4*)&raw[s][rr + 2][xc];
        cx = bq;
        float4 o;
        o.x = (1.f - a.x) * (1.f - bq.x) * (1.f - c.x);
        o.y = (1.f - a.y) * (1.f - bq.y) * (1.f - c.y);
        o.z = (1.f - a.z) * (1.f - bq.z) * (1.f - c.z);
        o.w = (1.f - a.w) * (1.f - bq.w) * (1.f - c.w);
        return o;
    };

    // ---- prologue: stage z0-1, z0, z0+1; pend loads for z0+2 ----
    stage_direct(z0 - 1);
    stage_direct(z0);
    stage_direct(z0 + 1);
    float4 pA = gload(z0 + 2, rr);
    float4 pB = (t < 64) ? gload(z0 + 2, xrow) : Z4;
    __syncthreads();   // one full drain in the prologue is fine
    float4 cxd, cx0;
    float4 ypm1 = yprod((z0 - 1) & 3, cxd);
    float4 yp0 = yprod(z0 & 3, cx0);
    unsigned mcur = *(const unsigned*)(mb + ((z0 << 14) | mrow | xc));

    float fp = 0.f, fn = 0.f, sx = 0.f, sy = 0.f;

#pragma unroll
    for (int dz = 0; dz < ZC; ++dz) {
        const int z = z0 + dz;

        // Phase 1: issue NEXT prefetch (slice z+3) + mask row of slice z+1.
        float4 nA = Z4, nB = Z4;
        if (dz <= ZC - 3) {
            nA = gload(z + 3, rr);
            if (t < 64) nB = gload(z + 3, xrow);
        }
        unsigned mnext = 0;
        if (dz <= ZC - 2)
            mnext = *(const unsigned*)(mb + (((z + 1) << 14) | mrow | xc));

        // Phase 2: y-products of slice z+1 from LDS (register ring fill)
        float4 cx1;
        const float4 ypp1 = yprod((z + 1) & 3, cx1);

        // Phase 3: compute voxels of slice z (registers only)
        {
            const float zp0 = ypm1.x * yp0.x * ypp1.x;
            const float zp1 = ypm1.y * yp0.y * ypp1.y;
            const float zp2 = ypm1.z * yp0.z * ypp1.z;
            const float zp3 = ypm1.w * yp0.w * ypp1.w;
            float zl = __shfl_up(zp3, 1);
            if ((t & 31) == 0) zl = 1.f;
            float zr = __shfl_down(zp0, 1);
            if ((t & 31) == 31) zr = 1.f;
            const float t01 = zp0 * zp1, t12 = zp1 * zp2, t23 = zp2 * zp3;
            const float P[4] = {zl * t01, t01 * zp2, t12 * zp3, t23 * zr};
            const float xa[4] = {cx0.x, cx0.y, cx0.z, cx0.w};
#pragma unroll
            for (int j = 0; j < 4; ++j) {
                const int m = (mcur >> (j * 8)) & 0xFF;
                const bool pres = (m >> cls) & 1;
                const bool eq = (m >> 4) == cls;
                const float xv = xa[j];
                sx += xv;
                fp += eq ? 0.f : xv * (pres ? 1.f : 2.f);
                fn += eq ? (1.f - xv) * (1.f + P[j]) : 0.f;
                sy += eq ? 1.f : 0.f;
            }
        }

        // Phase 4: write PREVIOUS pend (slice z+2) into its slot. The compiler
        // waits on pA/pB via a COUNTED vmcnt (nA/nB/mnext are younger and stay
        // outstanding).
        if (dz <= ZC - 2) {
            const int s = (z + 2) & 3;
            *(float4*)&raw[s][rr][xc] = pA;
            if (t < 64) *(float4*)&raw[s][xrow][xc] = pB;
        }

        // Counted barrier (T4): drain LDS writes only; global loads for z+3
        // remain in flight across the barrier. (__syncthreads would vmcnt(0).)
        asm volatile("s_waitcnt lgkmcnt(0)" ::: "memory");
        __builtin_amdgcn_s_barrier();

        // rotate register rings
        pA = nA; pB = nB;
        ypm1 = yp0; yp0 = ypp1; cx0 = cx1; mcur = mnext;
    }

    // ---- reduce 4 scalars: wave shuffle -> block LDS -> global atomics ----
    float rr4[4] = {fp, fn, sx, sy};
#pragma unroll
    for (int i = 0; i < 4; ++i) {
        float vv = rr4[i];
#pragma unroll
        for (int off = 32; off >= 1; off >>= 1) vv += __shfl_down(vv, off);
        rr4[i] = vv;
    }
    if (t < 4) sred[t] = 0.f;
    __syncthreads();
    if (lane == 0) {
#pragma unroll
        for (int i = 0; i < 4; ++i) atomicAdd(&sred[i], rr4[i]);
    }
    __syncthreads();
    if (t < 4)
        atomicAdd(&acc[b * 16 + t * 4 + cls], sred[t]);
}

// ===========================================================================
// K2: finalize scalar loss
// ===========================================================================
__global__ void lah_finalize(const float* __restrict__ acc, float* __restrict__ out) {
    float loss = 0.f;
#pragma unroll
    for (int b = 0; b < 2; ++b) {
#pragma unroll
        for (int c = 1; c < 4; ++c) {
            const float fp = acc[b * 16 + 0 + c];
            const float fn = acc[b * 16 + 4 + c];
            const float sxv = acc[b * 16 + 8 + c];
            const float syv = acc[b * 16 + 12 + c];
            loss += fmaxf(fp / (sxv + EPSV), fn / (syv + EPSV));
        }
    }
    out[0] = loss / 6.f;
}

extern "C" void kernel_launch(void* const* d_in, const int* in_sizes, int n_in,
                              void* d_out, int out_size, void* d_ws, size_t ws_size,
                              hipStream_t stream) {
    const float* x = (const float*)d_in[0];
    const int* y32 = (const int*)d_in[1];
    float* out = (float*)d_out;
    float* acc = (float*)d_ws;  // 32 floats

    hipMemsetAsync(d_ws, 0, 32 * sizeof(float), stream);
    mask_build<<<K0_NBLK, 256, 0, stream>>>(y32);
    lah_main<<<NBLK, 256, 0, stream>>>(x, acc);
    lah_finalize<<<1, 1, 0, stream>>>(acc, out);
}

// Round 12
// 53.008 us; speedup vs baseline: 1.2291x; 1.2291x over previous
//
#include <hip/hip_runtime.h>

// x[2][4][128][128][128] f32, y[2][1][128][128][128] int32
constexpr int SPB = 1 << 21;
constexpr float EPSV = 1e-6f;

// Static scratch: packed per-voxel mask, 4 MB.
// mask[v] = (center_class << 4) | OR_{3x3x3 clipped}(1 << y[v+d])
__device__ unsigned char g_mask[2 * SPB];

// ===========================================================================
// K0: build packed 27-neighborhood presence mask + center class (proven R5)
// ===========================================================================
constexpr int K0_ZSEG = 4;
constexpr int K0_NBLK = (2 * (128 / K0_ZSEG) * 128) / 4;  // 2048

struct MEnt { int pk, cx, cy; };

__device__ __forceinline__ MEnt k0_load(const int* __restrict__ yb, int s,
                                        int rbase0, bool ym1, bool yp1) {
    MEnt e;
    const int rb = (s << 14) | rbase0;
    int2 vc = *(const int2*)(yb + rb);
    int nib0 = 1 << vc.x, nib1 = 1 << vc.y;
    if (ym1) { int2 vm = *(const int2*)(yb + rb - 128); nib0 |= 1 << vm.x; nib1 |= 1 << vm.y; }
    if (yp1) { int2 vp = *(const int2*)(yb + rb + 128); nib0 |= 1 << vp.x; nib1 |= 1 << vp.y; }
    e.pk = nib0 | (nib1 << 8);
    e.cx = vc.x; e.cy = vc.y;
    return e;
}

__global__ __launch_bounds__(256) void mask_build(const int* __restrict__ y32) {
    const int wid = (blockIdx.x << 2) | (threadIdx.x >> 6);
    const int lane = threadIdx.x & 63;
    const int yy = wid & 127;
    const int zs = (wid >> 7) & 31;
    const int b = (wid >> 12) & 1;
    const int x0 = lane << 1;
    const int z0 = zs * K0_ZSEG;
    const bool ym1 = yy > 0, yp1 = yy < 127;
    const int rbase0 = (yy << 7) | x0;

    const int* __restrict__ yb = y32 + ((long)b << 21);
    unsigned char* __restrict__ mb = g_mask + ((long)b << 21);

    MEnt e0, e1;
    if (z0 > 0) e0 = k0_load(yb, z0 - 1, rbase0, ym1, yp1);
    else { e0.pk = 0; e0.cx = 0; e0.cy = 0; }
    e1 = k0_load(yb, z0, rbase0, ym1, yp1);

#pragma unroll
    for (int dz = 0; dz < K0_ZSEG; ++dz) {
        const int z = z0 + dz;
        MEnt e2;
        if (z + 1 < 128) e2 = k0_load(yb, z + 1, rbase0, ym1, yp1);
        else { e2.pk = 0; e2.cx = 0; e2.cy = 0; }

        const int zor = e0.pk | e1.pk | e2.pk;
        int orL = __shfl_up(zor, 1);
        if (lane == 0) orL = 0;
        int orR = __shfl_down(zor, 1);
        if (lane == 63) orR = 0;
        const int full0 = (zor | (zor >> 8) | (orL >> 8)) & 15;
        const int full1 = (zor | (zor >> 8) | orR) & 15;

        const unsigned short st =
            (unsigned short)((full0 | (e1.cx << 4)) | ((full1 | (e1.cy << 4)) << 8));
        *(unsigned short*)(mb + ((z << 14) | rbase0)) = st;

        e0 = e1; e1 = e2;
    }
}

// ===========================================================================
// K1: WAVE-PRIVATE stencil, ZERO barriers in the loop.
// Wave = (plane, row-pair rp, z-chunk). Stages rows 2rp-1..2rp+2 of each
// slice into a private LDS ring of 4 slices (8 KB/wave, 32 KB/block).
// Loads issued distance-2 (two iterations of slack -> counted vmcnt at the
// deferred ds_write). No cross-wave LDS -> no s_barrier -> no vmcnt drain.
// ===========================================================================
constexpr int ZC = 8;
constexpr int NBLK = 8 * 16 * (128 / ZC);   // planes * row-quads * z-chunks = 2048

__global__ __launch_bounds__(256) void lah_main(const float* __restrict__ x,
                                                float* __restrict__ acc) {
    __shared__ float lds[4][4][4][128];   // [wave][slot][local row][x] = 32 KB
    __shared__ float sred[4];

    const int bid = blockIdx.x;
    const int plane = bid & 7;            // -> XCD (round-robin dispatch)
    const int b = plane >> 2, cls = plane & 3;
    const int inner = bid >> 3;           // 0..255
    const int quad = inner & 15;          // row-pair quad
    const int zq = inner >> 4;            // 0..15
    const int t = threadIdx.x;
    const int w = t >> 6;                 // wave in block
    const int rp = quad * 4 + w;          // row-pair 0..63
    const int lane = t & 63;
    const int half = lane >> 5;           // 0 or 1
    const int lx = lane & 31;
    const int xc = lx << 2;               // x positions xc..xc+3
    const int z0 = zq * ZC;               // multiple of 8 -> z0 & 3 == 0

    const int rowA = 2 * rp - 1 + half;   // staged rows: 2rp-1, 2rp
    const int rowB = 2 * rp + 1 + half;   //              2rp+1, 2rp+2
    const int rout = 2 * rp + half;       // this lane's output row
    const bool okA = rowA >= 0;
    const bool okB = rowB <= 127;

    const float* __restrict__ xp = x + ((long)plane << 21);
    const unsigned char* __restrict__ mb = g_mask + ((long)b << 21);

    const float4 Z4 = make_float4(0.f, 0.f, 0.f, 0.f);

    auto gloadA = [&](int k) -> float4 {
        if ((unsigned)k > 127u || !okA) return Z4;
        return *(const float4*)(xp + ((k << 14) | (rowA << 7) | xc));
    };
    auto gloadB = [&](int k) -> float4 {
        if ((unsigned)k > 127u || !okB) return Z4;
        return *(const float4*)(xp + ((k << 14) | (rowB << 7) | xc));
    };
    auto lmask = [&](int k) -> unsigned {
        return *(const unsigned*)(mb + ((k << 14) | (rout << 7) | xc));
    };
    auto wslice = [&](int k, float4 a, float4 bb) {
        const int s = k & 3;
        *(float4*)&lds[w][s][half][xc] = a;          // rows 2rp-1 / 2rp
        *(float4*)&lds[w][s][2 + half][xc] = bb;     // rows 2rp+1 / 2rp+2
    };
    // y-product of (1-x) over rows rout-1..rout+1 of slice slot; center -> cx
    auto yprod = [&](int k, float4& cx) -> float4 {
        const int s = k & 3;
        const float4 a = *(const float4*)&lds[w][s][half][xc];
        const float4 bq = *(const float4*)&lds[w][s][half + 1][xc];
        const float4 c = *(const float4*)&lds[w][s][half + 2][xc];
        cx = bq;
        float4 o;
        o.x = (1.f - a.x) * (1.f - bq.x) * (1.f - c.x);
        o.y = (1.f - a.y) * (1.f - bq.y) * (1.f - c.y);
        o.z = (1.f - a.z) * (1.f - bq.z) * (1.f - c.z);
        o.w = (1.f - a.w) * (1.f - bq.w) * (1.f - c.w);
        return o;
    };

    // ---- prologue: stage z0-1, z0; pend loads for z0+1 (p0) and z0+2 (p1) ----
    {
        float4 a0 = gloadA(z0 - 1), b0 = gloadB(z0 - 1);
        float4 a1 = gloadA(z0),     b1 = gloadB(z0);
        wslice(z0 - 1, a0, b0);
        wslice(z0, a1, b1);
    }
    float4 p0A = gloadA(z0 + 1), p0B = gloadB(z0 + 1);
    float4 p1A = gloadA(z0 + 2), p1B = gloadB(z0 + 2);
    unsigned mcur = lmask(z0);
    float4 cxd, cx0;
    float4 ypm1 = yprod(z0 - 1, cxd);
    float4 yp0 = yprod(z0, cx0);

    float fp = 0.f, fn = 0.f, sx = 0.f, sy = 0.f;

#pragma unroll 4
    for (int dz = 0; dz < ZC; ++dz) {
        const int z = z0 + dz;

        // Phase 1: issue loads for slice z+3 (distance-2) + mask of slice z+1
        float4 nA = Z4, nB = Z4;
        if (dz <= ZC - 3) { nA = gloadA(z + 3); nB = gloadB(z + 3); }
        unsigned mnx = 0;
        if (dz <= ZC - 2) mnx = lmask(z + 1);

        // Phase 2: write slice z+1 from p0 (loads issued TWO iterations ago;
        // compiler waits with a counted vmcnt, fresh loads stay in flight)
        wslice(z + 1, p0A, p0B);

        // Phase 3: y-products of slice z+1 (same-wave DS ordering, no barrier)
        float4 cx1;
        const float4 ypp1 = yprod(z + 1, cx1);

        // Phase 4: compute voxels of slice z (registers only)
        {
            const float zp0 = ypm1.x * yp0.x * ypp1.x;
            const float zp1 = ypm1.y * yp0.y * ypp1.y;
            const float zp2 = ypm1.z * yp0.z * ypp1.z;
            const float zp3 = ypm1.w * yp0.w * ypp1.w;
            float zl = __shfl_up(zp3, 1);
            if (lx == 0) zl = 1.f;
            float zr = __shfl_down(zp0, 1);
            if (lx == 31) zr = 1.f;
            const float t01 = zp0 * zp1, t12 = zp1 * zp2, t23 = zp2 * zp3;
            const float P[4] = {zl * t01, t01 * zp2, t12 * zp3, t23 * zr};
            const float xa[4] = {cx0.x, cx0.y, cx0.z, cx0.w};
#pragma unroll
            for (int j = 0; j < 4; ++j) {
                const int m = (mcur >> (j * 8)) & 0xFF;
                const bool pres = (m >> cls) & 1;
                const bool eq = (m >> 4) == cls;
                const float xv = xa[j];
                sx += xv;
                fp += eq ? 0.f : xv * (pres ? 1.f : 2.f);
                fn += eq ? (1.f - xv) * (1.f + P[j]) : 0.f;
                sy += eq ? 1.f : 0.f;
            }
        }

        // rotate pend and register rings
        p0A = p1A; p0B = p1B; p1A = nA; p1B = nB;
        ypm1 = yp0; yp0 = ypp1; cx0 = cx1; mcur = mnx;
    }

    // ---- reduce 4 scalars: wave shuffle -> block LDS -> global atomics ----
    float rr4[4] = {fp, fn, sx, sy};
#pragma unroll
    for (int i = 0; i < 4; ++i) {
        float vv = rr4[i];
#pragma unroll
        for (int off = 32; off >= 1; off >>= 1) vv += __shfl_down(vv, off);
        rr4[i] = vv;
    }
    if (t < 4) sred[t] = 0.f;
    __syncthreads();
    if (lane == 0) {
#pragma unroll
        for (int i = 0; i < 4; ++i) atomicAdd(&sred[i], rr4[i]);
    }
    __syncthreads();
    if (t < 4)
        atomicAdd(&acc[b * 16 + t * 4 + cls], sred[t]);
}

// ===========================================================================
// K2: finalize scalar loss
// ===========================================================================
__global__ void lah_finalize(const float* __restrict__ acc, float* __restrict__ out) {
    float loss = 0.f;
#pragma unroll
    for (int b = 0; b < 2; ++b) {
#pragma unroll
        for (int c = 1; c < 4; ++c) {
            const float fp = acc[b * 16 + 0 + c];
            const float fn = acc[b * 16 + 4 + c];
            const float sxv = acc[b * 16 + 8 + c];
            const float syv = acc[b * 16 + 12 + c];
            loss += fmaxf(fp / (sxv + EPSV), fn / (syv + EPSV));
        }
    }
    out[0] = loss / 6.f;
}

extern "C" void kernel_launch(void* const* d_in, const int* in_sizes, int n_in,
                              void* d_out, int out_size, void* d_ws, size_t ws_size,
                              hipStream_t stream) {
    const float* x = (const float*)d_in[0];
    const int* y32 = (const int*)d_in[1];
    float* out = (float*)d_out;
    float* acc = (float*)d_ws;  // 32 floats

    hipMemsetAsync(d_ws, 0, 32 * sizeof(float), stream);
    mask_build<<<K0_NBLK, 256, 0, stream>>>(y32);
    lah_main<<<NBLK, 256, 0, stream>>>(x, acc);
    lah_finalize<<<1, 1, 0, stream>>>(acc, out);
}

// Round 13
// 47.411 us; speedup vs baseline: 1.3742x; 1.1181x over previous
//
#include <hip/hip_runtime.h>

// x[2][4][128][128][128] f32, y[2][1][128][128][128] int32
constexpr int SPB = 1 << 21;
constexpr float EPSV = 1e-6f;

// Static scratch: packed per-voxel mask, 4 MB.
// mask[v] = (center_class << 4) | OR_{3x3x3 clipped}(1 << y[v+d])
__device__ unsigned char g_mask[2 * SPB];

// ===========================================================================
// K0: build packed 27-neighborhood presence mask + center class (proven R5)
// ===========================================================================
constexpr int K0_ZSEG = 4;
constexpr int K0_NBLK = (2 * (128 / K0_ZSEG) * 128) / 4;  // 2048

struct MEnt { int pk, cx, cy; };

__device__ __forceinline__ MEnt k0_load(const int* __restrict__ yb, int s,
                                        int rbase0, bool ym1, bool yp1) {
    MEnt e;
    const int rb = (s << 14) | rbase0;
    int2 vc = *(const int2*)(yb + rb);
    int nib0 = 1 << vc.x, nib1 = 1 << vc.y;
    if (ym1) { int2 vm = *(const int2*)(yb + rb - 128); nib0 |= 1 << vm.x; nib1 |= 1 << vm.y; }
    if (yp1) { int2 vp = *(const int2*)(yb + rb + 128); nib0 |= 1 << vp.x; nib1 |= 1 << vp.y; }
    e.pk = nib0 | (nib1 << 8);
    e.cx = vc.x; e.cy = vc.y;
    return e;
}

__global__ __launch_bounds__(256) void mask_build(const int* __restrict__ y32) {
    const int wid = (blockIdx.x << 2) | (threadIdx.x >> 6);
    const int lane = threadIdx.x & 63;
    const int yy = wid & 127;
    const int zs = (wid >> 7) & 31;
    const int b = (wid >> 12) & 1;
    const int x0 = lane << 1;
    const int z0 = zs * K0_ZSEG;
    const bool ym1 = yy > 0, yp1 = yy < 127;
    const int rbase0 = (yy << 7) | x0;

    const int* __restrict__ yb = y32 + ((long)b << 21);
    unsigned char* __restrict__ mb = g_mask + ((long)b << 21);

    MEnt e0, e1;
    if (z0 > 0) e0 = k0_load(yb, z0 - 1, rbase0, ym1, yp1);
    else { e0.pk = 0; e0.cx = 0; e0.cy = 0; }
    e1 = k0_load(yb, z0, rbase0, ym1, yp1);

#pragma unroll
    for (int dz = 0; dz < K0_ZSEG; ++dz) {
        const int z = z0 + dz;
        MEnt e2;
        if (z + 1 < 128) e2 = k0_load(yb, z + 1, rbase0, ym1, yp1);
        else { e2.pk = 0; e2.cx = 0; e2.cy = 0; }

        const int zor = e0.pk | e1.pk | e2.pk;
        int orL = __shfl_up(zor, 1);
        if (lane == 0) orL = 0;
        int orR = __shfl_down(zor, 1);
        if (lane == 63) orR = 0;
        const int full0 = (zor | (zor >> 8) | (orL >> 8)) & 15;
        const int full1 = (zor | (zor >> 8) | orR) & 15;

        const unsigned short st =
            (unsigned short)((full0 | (e1.cx << 4)) | ((full1 | (e1.cy << 4)) << 8));
        *(unsigned short*)(mb + ((z << 14) | rbase0)) = st;

        e0 = e1; e1 = e2;
    }
}

// ===========================================================================
// K1: wave-private tiles staged via global_load_lds (async DMA, no pend VGPRs,
// no ds_write, NO barriers in loop). Ring-of-2 slots per wave (4 KB each).
// Exactly 3 VMEM ops issued per iteration -> explicit counted vmcnt(3) waits
// only on the loads issued one iteration earlier; fresh loads stay in flight.
// ===========================================================================
constexpr int ZC = 8;
constexpr int NBLK = 8 * 16 * (128 / ZC);   // planes * row-quads * z-chunks = 2048

__global__ __launch_bounds__(256) void lah_main(const float* __restrict__ x,
                                                float* __restrict__ ws) {
    __shared__ float lds[4][2][4][128];   // [wave][slot][local row][x] = 16 KB
    __shared__ float sred[4];

    float* acc = ws;                       // 32 floats (zeroed by host memset)
    const float* zp = ws + 64;             // 16B zero page (also zeroed)

    const int bid = blockIdx.x;
    const int plane = bid & 7;            // -> XCD (round-robin dispatch)
    const int b = plane >> 2, cls = plane & 3;
    const int inner = bid >> 3;           // 0..255
    const int quad = inner & 15;          // row-pair quad
    const int zq = inner >> 4;            // 0..15
    const int t = threadIdx.x;
    const int w = t >> 6;                 // wave in block
    const int rp = quad * 4 + w;          // row-pair 0..63
    const int lane = t & 63;
    const int hf = lane >> 5;             // 0 or 1
    const int lx = lane & 31;
    const int xc = lx << 2;               // float/byte x offset (4 voxels)
    const int z0 = zq * ZC;

    const int rowA = 2 * rp - 1 + hf;     // staged rows (call 1): 2rp-1, 2rp
    const int rowB = 2 * rp + 1 + hf;     // staged rows (call 2): 2rp+1, 2rp+2
    const int rout = 2 * rp + hf;         // this lane's output row
    const bool okA = rowA >= 0;
    const bool okB = rowB <= 127;
    const int offA = (rowA << 7) + xc;    // per-lane float offset within slice
    const int offB = (rowB << 7) + xc;

    const float* __restrict__ xp = x + ((long)plane << 21);
    const unsigned char* __restrict__ mb = g_mask + ((long)b << 21);

    // stage slice k into slot (k&1): 2x global_load_lds, 16B/lane each.
    // lane l of call1 -> LDS bytes [16l,16l+16) = local row (l>>5), x (l&31)*16B
    // which matches source row rowA(l), col xc(l). OOB lanes/slices -> zero page.
    auto stage = [&](int k, bool want) {
        const int sl = k & 1;
        const bool kOK = want && ((unsigned)k < 128u);
        const float* pa = (kOK && okA) ? (xp + (k << 14) + offA) : zp;
        const float* pb = (kOK && okB) ? (xp + (k << 14) + offB) : zp;
        __builtin_amdgcn_global_load_lds(
            (const __attribute__((address_space(1))) void*)pa,
            (__attribute__((address_space(3))) void*)&lds[w][sl][0][0], 16, 0, 0);
        __builtin_amdgcn_global_load_lds(
            (const __attribute__((address_space(1))) void*)pb,
            (__attribute__((address_space(3))) void*)&lds[w][sl][2][0], 16, 0, 0);
    };
    auto lmask = [&](int k) -> unsigned {
        const int kc = k < 127 ? k : 127;
        return *(const unsigned*)(mb + (kc << 14) + (rout << 7) + xc);
    };
    // y-product of (1-x) over local rows hf..hf+2 of slot sl; center raw -> cx
    auto yprod = [&](int sl, float4& cx) -> float4 {
        const float4 a = *(const float4*)&lds[w][sl][hf][xc];
        const float4 bq = *(const float4*)&lds[w][sl][hf + 1][xc];
        const float4 c = *(const float4*)&lds[w][sl][hf + 2][xc];
        cx = bq;
        float4 o;
        o.x = (1.f - a.x) * (1.f - bq.x) * (1.f - c.x);
        o.y = (1.f - a.y) * (1.f - bq.y) * (1.f - c.y);
        o.z = (1.f - a.z) * (1.f - bq.z) * (1.f - c.z);
        o.w = (1.f - a.w) * (1.f - bq.w) * (1.f - c.w);
        return o;
    };

    // ---- prologue ----
    stage(z0 - 1, true);                   // slot 1 (zero page if z0 == 0)
    stage(z0, true);                       // slot 0
    asm volatile("s_waitcnt vmcnt(0)" ::: "memory");
    float4 cxd, cx0;
    float4 ypm1 = yprod(1, cxd);
    float4 yp0 = yprod(0, cx0);
    asm volatile("s_waitcnt lgkmcnt(0)" ::: "memory");  // reads retired before slot1 reuse
    stage(z0 + 1, true);                   // slot 1
    unsigned mcur = lmask(z0);
    // invariant at loop top: 3 VMEM outstanding = {gll(z+1) x2, mask(z)}

    float fp = 0.f, fn = 0.f, sx = 0.f, sy = 0.f;

#pragma unroll
    for (int dz = 0; dz < ZC; ++dz) {
        const int z = z0 + dz;

        // Phase 1: issue staging of slice z+2 (slot z&1, currently dead) + mask z+1
        stage(z + 2, dz < ZC - 1);
        const unsigned mnext = lmask(z + 1);

        // Phase 2: counted wait -- completes gll(z+1) pair and mask(z) only;
        // the 3 just-issued ops stay in flight through the whole compute.
        asm volatile("s_waitcnt vmcnt(3)" ::: "memory");

        // Phase 3: y-products of slice z+1
        float4 cx1;
        const float4 ypp1 = yprod((z + 1) & 1, cx1);

        // Phase 4: compute voxels of slice z (registers only)
        {
            const float zp0 = ypm1.x * yp0.x * ypp1.x;
            const float zp1 = ypm1.y * yp0.y * ypp1.y;
            const float zp2 = ypm1.z * yp0.z * ypp1.z;
            const float zp3 = ypm1.w * yp0.w * ypp1.w;
            float zl = __shfl_up(zp3, 1);
            if (lx == 0) zl = 1.f;
            float zr = __shfl_down(zp0, 1);
            if (lx == 31) zr = 1.f;
            const float t01 = zp0 * zp1, t12 = zp1 * zp2, t23 = zp2 * zp3;
            const float P[4] = {zl * t01, t01 * zp2, t12 * zp3, t23 * zr};
            const float xa[4] = {cx0.x, cx0.y, cx0.z, cx0.w};
#pragma unroll
            for (int j = 0; j < 4; ++j) {
                const int m = (mcur >> (j * 8)) & 0xFF;
                const bool pres = (m >> cls) & 1;
                const bool eq = (m >> 4) == cls;
                const float xv = xa[j];
                sx += xv;
                fp += eq ? 0.f : xv * (pres ? 1.f : 2.f);
                fn += eq ? (1.f - xv) * (1.f + P[j]) : 0.f;
                sy += eq ? 1.f : 0.f;
            }
        }

        // rotate register rings
        ypm1 = yp0; yp0 = ypp1; cx0 = cx1; mcur = mnext;
    }

    // ---- reduce 4 scalars: wave shuffle -> block LDS -> global atomics ----
    float rr4[4] = {fp, fn, sx, sy};
#pragma unroll
    for (int i = 0; i < 4; ++i) {
        float vv = rr4[i];
#pragma unroll
        for (int off = 32; off >= 1; off >>= 1) vv += __shfl_down(vv, off);
        rr4[i] = vv;
    }
    if (t < 4) sred[t] = 0.f;
    __syncthreads();
    if (lane == 0) {
#pragma unroll
        for (int i = 0; i < 4; ++i) atomicAdd(&sred[i], rr4[i]);
    }
    __syncthreads();
    if (t < 4)
        atomicAdd(&acc[b * 16 + t * 4 + cls], sred[t]);
}

// ===========================================================================
// K2: finalize scalar loss
// ===========================================================================
__global__ void lah_finalize(const float* __restrict__ acc, float* __restrict__ out) {
    float loss = 0.f;
#pragma unroll
    for (int b = 0; b < 2; ++b) {
#pragma unroll
        for (int c = 1; c < 4; ++c) {
            const float fp = acc[b * 16 + 0 + c];
            const float fn = acc[b * 16 + 4 + c];
            const float sxv = acc[b * 16 + 8 + c];
            const float syv = acc[b * 16 + 12 + c];
            loss += fmaxf(fp / (sxv + EPSV), fn / (syv + EPSV));
        }
    }
    out[0] = loss / 6.f;
}

extern "C" void kernel_launch(void* const* d_in, const int* in_sizes, int n_in,
                              void* d_out, int out_size, void* d_ws, size_t ws_size,
                              hipStream_t stream) {
    const float* x = (const float*)d_in[0];
    const int* y32 = (const int*)d_in[1];
    float* out = (float*)d_out;
    float* ws = (float*)d_ws;   // [0..31] acc, [64..] zero page

    hipMemsetAsync(d_ws, 0, 4096, stream);
    mask_build<<<K0_NBLK, 256, 0, stream>>>(y32);
    lah_main<<<NBLK, 256, 0, stream>>>(x, ws);
    lah_finalize<<<1, 1, 0, stream>>>(ws, out);
}